// Round 6
// baseline (50.886 us; speedup 1.0000x reference)
//
#include <hip/hip_runtime.h>

#define N_RBF 16
#define N_HIDDEN 32
#define BLOCK 512                 // 8 waves; block owns 4 atoms
#define NW 8
#define QCAP 128                  // per-(wave,atom) d2 ring (power of 2)

// Gaussian-grid recurrence (a = 4.5, w = 1/3):
//   r_k = exp(-a (d - k w)^2); r_0 = exp(-a d^2); r_{k+1} = r_k * s_k,
//   s_k = exp(3d - 0.5 - k).  Even/odd split for ILP.
// Chain scaled by 2^80 so r_0 never underflows for d < 5.
#define LOG2E 1.44269504088896340736f
#define NC   (-4.5f * LOG2E)
#define S0A  (3.0f * LOG2E)
#define S0B  (-0.5f * LOG2E)
#define BIAS 80.0f
#define UNSC 8.271806125530277e-25f     // 2^-80
#define C_E1 0.36787944117144233f       // e^-1
#define C_E3 0.049787068367863944f      // e^-3
#define C_E4 0.018315638888734179f      // e^-4

__device__ __forceinline__ float rfl(float x) {
    return __int_as_float(__builtin_amdgcn_readfirstlane(__float_as_int(x)));
}

__device__ __forceinline__ void rbf_batch(float d2, bool active, float (&feat)[N_RBF]) {
    float d  = __builtin_amdgcn_sqrtf(d2);
    float r0 = __builtin_amdgcn_exp2f(fmaf(d2, NC, BIAS));   // 2^80 * exp(-a d^2)
    float s  = __builtin_amdgcn_exp2f(fmaf(d, S0A, S0B));    // exp(3d - 0.5)
    float r1 = r0 * s;
    if (!active) { r0 = 0.0f; r1 = 0.0f; }
    float s2 = s * s;
    float ue = s2 * C_E1;
    float uo = s2 * C_E3;
    #pragma unroll
    for (int k = 0; k < N_RBF; k += 2) {
        feat[k]     += r0;
        feat[k + 1] += r1;
        r0 *= ue;  r1 *= uo;
        ue *= C_E4; uo *= C_E4;
    }
}

// Transpose-reduce 16 per-lane partial features across 64 lanes.
// Returns: lanes with (lane&3)==0 hold the wave-sum of feature k=(lane>>2).
__device__ __forceinline__ float treduce(float (&f)[N_RBF], int lane) {
    float w1r[8];
    #pragma unroll
    for (int k = 0; k < 8; ++k) {
        float lo = f[k], hi = f[k + 8];
        float lo2 = __shfl_xor(lo, 32, 64);
        float hi2 = __shfl_xor(hi, 32, 64);
        w1r[k] = (lane & 32) ? (hi + hi2) : (lo + lo2);
    }
    float w2r[4];
    #pragma unroll
    for (int k = 0; k < 4; ++k) {
        float lo = w1r[k], hi = w1r[k + 4];
        float lo2 = __shfl_xor(lo, 16, 64);
        float hi2 = __shfl_xor(hi, 16, 64);
        w2r[k] = (lane & 16) ? (hi + hi2) : (lo + lo2);
    }
    float w3r[2];
    #pragma unroll
    for (int k = 0; k < 2; ++k) {
        float lo = w2r[k], hi = w2r[k + 2];
        float lo2 = __shfl_xor(lo, 8, 64);
        float hi2 = __shfl_xor(hi, 8, 64);
        w3r[k] = (lane & 8) ? (hi + hi2) : (lo + lo2);
    }
    float lo2 = __shfl_xor(w3r[0], 4, 64);
    float hi2 = __shfl_xor(w3r[1], 4, 64);
    float w4 = (lane & 4) ? (w3r[1] + hi2) : (w3r[0] + lo2);
    w4 += __shfl_xor(w4, 2, 64);
    w4 += __shfl_xor(w4, 1, 64);
    return w4;
}

__global__ __launch_bounds__(256)
void pack_kernel(const float* __restrict__ pos, float4* __restrict__ ppos,
                 float* __restrict__ out, int n, int npad)
{
    int i = blockIdx.x * 256 + threadIdx.x;
    if (i == 0) out[0] = 0.0f;
    if (i < npad) {
        float4 v;
        if (i < n) { v.x = pos[3*i]; v.y = pos[3*i+1]; v.z = pos[3*i+2]; v.w = 0.f; }
        else       { v.x = 1e9f;     v.y = 1e9f;       v.z = 1e9f;       v.w = 0.f; }
        ppos[i] = v;
    }
}

__global__ __launch_bounds__(BLOCK, 6)
void ag3sr_main(const float4* __restrict__ ppos,   // [npad] sentinel-padded
                const float* __restrict__ W1,      // [16,32]
                const float* __restrict__ b1,      // [32]
                const float* __restrict__ W2,      // [32]
                const float* __restrict__ b2,      // [1]
                float* __restrict__ out,           // [1]
                int n, int seg)                    // seg = npad/4 (mult of 64)
{
    __shared__ float sq[NW * 2 * QCAP];            // 8 KB ring queues
    __shared__ float ffin[4][N_RBF];               // combined features, 4 atoms
    __shared__ float sW1[N_RBF * N_HIDDEN];
    __shared__ float sb1[N_HIDDEN], sW2[N_HIDDEN];

    const int tid   = threadIdx.x;
    const int wave  = tid >> 6;
    const int lane  = tid & 63;
    const int abase = blockIdx.x * 4;
    const int pair  = wave & 1;                    // which atom pair (0: a0,a1; 1: a2,a3)
    const int qseg  = wave >> 1;                   // which j quarter

    for (int idx = tid; idx < N_RBF * N_HIDDEN; idx += BLOCK) sW1[idx] = W1[idx];
    if (tid < N_HIDDEN) { sb1[tid] = b1[tid]; sW2[tid] = W2[tid]; }
    if (tid < 4 * N_RBF) ((float*)ffin)[tid] = 0.0f;

    // Two atom positions per wave, forced wave-uniform (SGPR operands)
    float4 pa = ppos[abase + pair * 2 + 0];
    float4 pb = ppos[abase + pair * 2 + 1];
    float xa = rfl(pa.x), ya = rfl(pa.y), za = rfl(pa.z);
    float xb = rfl(pb.x), yb = rfl(pb.y), zb = rfl(pb.z);

    float feat0[N_RBF], feat1[N_RBF];
    #pragma unroll
    for (int k = 0; k < N_RBF; ++k) { feat0[k] = 0.0f; feat1[k] = 0.0f; }

    const int base0 = (wave * 2 + 0) * QCAP;
    const int base1 = (wave * 2 + 1) * QCAP;
    int c0 = 0, p0 = 0, c1 = 0, p1 = 0;

    const int jbase = qseg * seg;
    const int iters = seg >> 6;

    #pragma unroll 2
    for (int it = 0; it < iters; ++it) {
        float4 pj = ppos[jbase + (it << 6) + lane];   // 1 load serves 128 pairs
        {   // atom A
            float dx = pj.x - xa, dy = pj.y - ya, dz = pj.z - za;
            float d2 = fmaf(dz, dz, fmaf(dy, dy, dx * dx));
            bool pass = (d2 > 0.0f) & (d2 < 25.0f);
            unsigned long long m = __ballot(pass);
            int prefix = __builtin_amdgcn_mbcnt_hi((unsigned)(m >> 32),
                          __builtin_amdgcn_mbcnt_lo((unsigned)m, 0u));
            if (pass) sq[base0 + ((c0 + prefix) & (QCAP - 1))] = d2;
            c0 += __popcll(m);
            if (c0 - p0 >= 64) {                       // wave-uniform drain
                float qd2 = sq[base0 + ((p0 + lane) & (QCAP - 1))];
                p0 += 64;
                rbf_batch(qd2, true, feat0);
            }
        }
        {   // atom B
            float dx = pj.x - xb, dy = pj.y - yb, dz = pj.z - zb;
            float d2 = fmaf(dz, dz, fmaf(dy, dy, dx * dx));
            bool pass = (d2 > 0.0f) & (d2 < 25.0f);
            unsigned long long m = __ballot(pass);
            int prefix = __builtin_amdgcn_mbcnt_hi((unsigned)(m >> 32),
                          __builtin_amdgcn_mbcnt_lo((unsigned)m, 0u));
            if (pass) sq[base1 + ((c1 + prefix) & (QCAP - 1))] = d2;
            c1 += __popcll(m);
            if (c1 - p1 >= 64) {
                float qd2 = sq[base1 + ((p1 + lane) & (QCAP - 1))];
                p1 += 64;
                rbf_batch(qd2, true, feat1);
            }
        }
    }

    // tail drains (rem in [0,63])
    {
        int rem = c0 - p0;
        if (rem > 0) {
            bool act = lane < rem;
            float qd2 = act ? sq[base0 + ((p0 + lane) & (QCAP - 1))] : 0.0f;
            rbf_batch(qd2, act, feat0);
        }
        rem = c1 - p1;
        if (rem > 0) {
            bool act = lane < rem;
            float qd2 = act ? sq[base1 + ((p1 + lane) & (QCAP - 1))] : 0.0f;
            rbf_batch(qd2, act, feat1);
        }
    }

    // Wave-reduce features; holder lanes add into block-combined ffin
    float w40 = treduce(feat0, lane);
    float w41 = treduce(feat1, lane);

    __syncthreads();   // ffin zeroed + weights staged before use
    if ((lane & 3) == 0) {
        int k = lane >> 2;                 // 0..15
        atomicAdd(&ffin[pair * 2 + 0][k], w40);
        atomicAdd(&ffin[pair * 2 + 1][k], w41);
    }
    __syncthreads();

    // MLP: threads 0..127 -> (atom a = tid>>5, hidden h = tid&31)
    if (tid < 128) {
        int a = tid >> 5, h = tid & 31;
        float acc = sb1[h];
        #pragma unroll
        for (int k = 0; k < N_RBF; ++k)
            acc = fmaf(ffin[a][k] * UNSC, sW1[k * N_HIDDEN + h], acc);
        float sg = 1.0f / (1.0f + __builtin_amdgcn_exp2f(-acc * LOG2E));
        float e = acc * sg * sW2[h];
        #pragma unroll
        for (int off = 16; off > 0; off >>= 1) e += __shfl_xor(e, off, 64);
        if (h == 0 && (abase + a) < n) atomicAdd(out, e + b2[0]);
    }
}

extern "C" void kernel_launch(void* const* d_in, const int* in_sizes, int n_in,
                              void* d_out, int out_size, void* d_ws, size_t ws_size,
                              hipStream_t stream) {
    const float* pos = (const float*)d_in[0];
    const float* W1  = (const float*)d_in[1];
    const float* b1  = (const float*)d_in[2];
    const float* W2  = (const float*)d_in[3];
    const float* b2  = (const float*)d_in[4];
    float* out = (float*)d_out;

    const int n    = in_sizes[0] / 3;
    const int npad = (n + 255) & ~255;      // 4 segments, each mult of 64
    const int seg  = npad >> 2;

    float4* ppos = (float4*)d_ws;           // 16*npad bytes of scratch

    pack_kernel<<<(npad + 255) / 256, 256, 0, stream>>>(pos, ppos, out, n, npad);

    const int grid = npad / 4;              // 4 atoms per block
    ag3sr_main<<<grid, BLOCK, 0, stream>>>(ppos, W1, b1, W2, b2, out, n, seg);
}

// Round 7
// 46.704 us; speedup vs baseline: 1.0895x; 1.0895x over previous
//
#include <hip/hip_runtime.h>

#define N_RBF 16
#define N_HIDDEN 32
#define BLOCK 256                 // 4 waves = 4 j-segments of one atom-pair
#define NSEG 4
#define QCAP 224                  // per-(wave,atom) queue capacity

// Gaussian-grid recurrence (a = 4.5, w = 1/3):
//   r_k = exp(-a (d - k w)^2); r_0 = exp(-a d^2); r_{k+1} = r_k * s_k,
//   s_k = exp(3d - 0.5 - k).  Even/odd split for ILP.
// Chain scaled by 2^80 so r_0 never underflows for d < 5.
#define LOG2E 1.44269504088896340736f
#define NC   (-4.5f * LOG2E)
#define S0A  (3.0f * LOG2E)
#define S0B  (-0.5f * LOG2E)
#define BIAS 80.0f
#define UNSC 8.271806125530277e-25f     // 2^-80
#define C_E1 0.36787944117144233f       // e^-1
#define C_E3 0.049787068367863944f      // e^-3
#define C_E4 0.018315638888734179f      // e^-4

__device__ __forceinline__ float rfl(float x) {
    return __int_as_float(__builtin_amdgcn_readfirstlane(__float_as_int(x)));
}

__device__ __forceinline__ void rbf_batch(float d2, bool active, float (&feat)[N_RBF]) {
    d2 = active ? d2 : 1.0f;          // masked lanes: benign arg, no inf/NaN in chain
    float d  = __builtin_amdgcn_sqrtf(d2);
    float r0 = __builtin_amdgcn_exp2f(fmaf(d2, NC, BIAS));   // 2^80 * exp(-a d^2)
    float s  = __builtin_amdgcn_exp2f(fmaf(d, S0A, S0B));    // exp(3d - 0.5)
    float r1 = r0 * s;
    if (!active) { r0 = 0.0f; r1 = 0.0f; }
    float s2 = s * s;
    float ue = s2 * C_E1;
    float uo = s2 * C_E3;
    #pragma unroll
    for (int k = 0; k < N_RBF; k += 2) {
        feat[k]     += r0;
        feat[k + 1] += r1;
        r0 *= ue;  r1 *= uo;
        ue *= C_E4; uo *= C_E4;
    }
}

// Transpose-reduce 16 per-lane partial features across 64 lanes.
// Lanes with (lane&3)==0 return the wave-sum of feature k=(lane>>2).
__device__ __forceinline__ float treduce(float (&f)[N_RBF], int lane) {
    float w1r[8];
    #pragma unroll
    for (int k = 0; k < 8; ++k) {
        float lo = f[k], hi = f[k + 8];
        float lo2 = __shfl_xor(lo, 32, 64);
        float hi2 = __shfl_xor(hi, 32, 64);
        w1r[k] = (lane & 32) ? (hi + hi2) : (lo + lo2);
    }
    float w2r[4];
    #pragma unroll
    for (int k = 0; k < 4; ++k) {
        float lo = w1r[k], hi = w1r[k + 4];
        float lo2 = __shfl_xor(lo, 16, 64);
        float hi2 = __shfl_xor(hi, 16, 64);
        w2r[k] = (lane & 16) ? (hi + hi2) : (lo + lo2);
    }
    float w3r[2];
    #pragma unroll
    for (int k = 0; k < 2; ++k) {
        float lo = w2r[k], hi = w2r[k + 2];
        float lo2 = __shfl_xor(lo, 8, 64);
        float hi2 = __shfl_xor(hi, 8, 64);
        w3r[k] = (lane & 8) ? (hi + hi2) : (lo + lo2);
    }
    float lo2 = __shfl_xor(w3r[0], 4, 64);
    float hi2 = __shfl_xor(w3r[1], 4, 64);
    float w4 = (lane & 4) ? (w3r[1] + hi2) : (w3r[0] + lo2);
    w4 += __shfl_xor(w4, 2, 64);
    w4 += __shfl_xor(w4, 1, 64);
    return w4;
}

__global__ __launch_bounds__(256)
void pack_kernel(const float* __restrict__ pos, float4* __restrict__ ppos,
                 float* __restrict__ out, int n, int npad)
{
    int i = blockIdx.x * 256 + threadIdx.x;
    if (i == 0) out[0] = 0.0f;
    if (i < npad) {
        float4 v;
        if (i < n) { v.x = pos[3*i]; v.y = pos[3*i+1]; v.z = pos[3*i+2]; v.w = 0.f; }
        else       { v.x = 1e9f;     v.y = 1e9f;       v.z = 1e9f;       v.w = 0.f; }
        ppos[i] = v;
    }
}

__global__ __launch_bounds__(BLOCK, 6)
void ag3sr_main(const float4* __restrict__ ppos,   // [npad] sentinel-padded
                const float* __restrict__ W1,      // [16,32]
                const float* __restrict__ b1,      // [32]
                const float* __restrict__ W2,      // [32]
                const float* __restrict__ b2,      // [1]
                float* __restrict__ out,           // [1]
                int n, int seg)                    // seg = npad/4 (mult of 64)
{
    __shared__ float sq[NSEG][2][QCAP];            // 7 KB queues
    __shared__ float sfeat[NSEG][2][N_RBF];        // per-wave partial features
    __shared__ float sW1[N_RBF * N_HIDDEN];
    __shared__ float sb1[N_HIDDEN], sW2[N_HIDDEN];

    const int tid  = threadIdx.x;
    const int wave = tid >> 6;                     // = j-segment index
    const int lane = tid & 63;
    const int a0   = blockIdx.x * 2;               // block owns atoms a0, a0+1

    for (int idx = tid; idx < N_RBF * N_HIDDEN; idx += BLOCK) sW1[idx] = W1[idx];
    if (tid < N_HIDDEN) { sb1[tid] = b1[tid]; sW2[tid] = W2[tid]; }

    float4 pa = ppos[a0];
    float4 pb = ppos[a0 + 1];
    float xa = rfl(pa.x), ya = rfl(pa.y), za = rfl(pa.z);
    float xb = rfl(pb.x), yb = rfl(pb.y), zb = rfl(pb.z);

    float feat0[N_RBF], feat1[N_RBF];
    #pragma unroll
    for (int k = 0; k < N_RBF; ++k) { feat0[k] = 0.0f; feat1[k] = 0.0f; }

    // ---- Phase A: branchless compaction (no mid-loop drains) ----
    int c0 = 0, c1 = 0;                            // wave-uniform counts (SGPR)
    const int jb = wave * seg;
    const int iters = seg >> 6;

    #pragma unroll 2
    for (int it = 0; it < iters; ++it) {
        float4 pj = ppos[jb + (it << 6) + lane];   // 1 load serves 128 pairs

        float dx0 = pj.x - xa, dy0 = pj.y - ya, dz0 = pj.z - za;
        float q0 = fmaf(dz0, dz0, fmaf(dy0, dy0, dx0 * dx0));
        bool p0 = (q0 > 0.0f) & (q0 < 25.0f);
        float dx1 = pj.x - xb, dy1 = pj.y - yb, dz1 = pj.z - zb;
        float q1 = fmaf(dz1, dz1, fmaf(dy1, dy1, dx1 * dx1));
        bool p1 = (q1 > 0.0f) & (q1 < 25.0f);

        unsigned long long m0 = __ballot(p0);
        int pr0 = __builtin_amdgcn_mbcnt_hi((unsigned)(m0 >> 32),
                   __builtin_amdgcn_mbcnt_lo((unsigned)m0, 0u));
        int sl0 = c0 + pr0;
        if (p0 && sl0 < QCAP) sq[wave][0][sl0] = q0;
        c0 += __popcll(m0);

        unsigned long long m1 = __ballot(p1);
        int pr1 = __builtin_amdgcn_mbcnt_hi((unsigned)(m1 >> 32),
                   __builtin_amdgcn_mbcnt_lo((unsigned)m1, 0u));
        int sl1 = c1 + pr1;
        if (p1 && sl1 < QCAP) sq[wave][1][sl1] = q1;
        c1 += __popcll(m1);

        if (c0 > QCAP || c1 > QCAP) {              // scalar branch, ~never taken:
            rbf_batch(q0, p0 && (sl0 >= QCAP), feat0);   // process overflow lanes
            rbf_batch(q1, p1 && (sl1 >= QCAP), feat1);   // immediately (exact)
        }
    }

    // ---- Phase B: dense drains, uniform bounds, pipelinable ds_reads ----
    {
        int st0 = c0 < QCAP ? c0 : QCAP;
        for (int b = 0; b < st0; b += 64) {
            bool act = (b + lane) < st0;
            float qd2 = sq[wave][0][act ? (b + lane) : 0];
            rbf_batch(qd2, act, feat0);
        }
        int st1 = c1 < QCAP ? c1 : QCAP;
        for (int b = 0; b < st1; b += 64) {
            bool act = (b + lane) < st1;
            float qd2 = sq[wave][1][act ? (b + lane) : 0];
            rbf_batch(qd2, act, feat1);
        }
    }

    // ---- Epilogue: wave-reduce, combine 4 segments, MLP ----
    float w40 = treduce(feat0, lane);
    float w41 = treduce(feat1, lane);
    if ((lane & 3) == 0) {
        int k = lane >> 2;
        sfeat[wave][0][k] = w40;
        sfeat[wave][1][k] = w41;
    }
    __syncthreads();

    if (tid < 64) {
        int a = tid >> 5, h = tid & 31;            // atom half, hidden unit
        float acc = sb1[h];
        #pragma unroll
        for (int k = 0; k < N_RBF; ++k) {
            float f = (sfeat[0][a][k] + sfeat[1][a][k] +
                       sfeat[2][a][k] + sfeat[3][a][k]) * UNSC;
            acc = fmaf(f, sW1[k * N_HIDDEN + h], acc);
        }
        float sg = 1.0f / (1.0f + __builtin_amdgcn_exp2f(-acc * LOG2E));
        float e = acc * sg * sW2[h];
        #pragma unroll
        for (int off = 16; off > 0; off >>= 1) e += __shfl_xor(e, off, 64);
        if (h == 0 && (a0 + a) < n) atomicAdd(out, e + b2[0]);
    }
}

extern "C" void kernel_launch(void* const* d_in, const int* in_sizes, int n_in,
                              void* d_out, int out_size, void* d_ws, size_t ws_size,
                              hipStream_t stream) {
    const float* pos = (const float*)d_in[0];
    const float* W1  = (const float*)d_in[1];
    const float* b1  = (const float*)d_in[2];
    const float* W2  = (const float*)d_in[3];
    const float* b2  = (const float*)d_in[4];
    float* out = (float*)d_out;

    const int n    = in_sizes[0] / 3;
    const int npad = (n + 255) & ~255;      // NSEG segments, each mult of 64
    const int seg  = npad / NSEG;

    float4* ppos = (float4*)d_ws;           // 16*npad bytes of scratch

    pack_kernel<<<(npad + 255) / 256, 256, 0, stream>>>(pos, ppos, out, n, npad);

    const int grid = npad / 2;               // 2 atoms per block
    ag3sr_main<<<grid, BLOCK, 0, stream>>>(ppos, W1, b1, W2, b2, out, n, seg);
}